// Round 5
// baseline (753.968 us; speedup 1.0000x reference)
//
#include <hip/hip_runtime.h>
#include <hip/hip_bf16.h>

// ============================================================================
// Hybrid matrix prefix scan:  res[k] = x @ (m_0 ... m_{k-1}),  N=1024, D=256.
// Deviation form everywhere: store P - I in bf16; combine is exact:
//   dev(XY) = devX + devY + devX@devY.
// Round 8 (traffic attack): retile gemm 64x64 -> 128x128, 4 blocks/mat.
//   Rationale: occupancy/VALU/launch theories all exonerated by R5-R7 washes;
//   byte-count model says the 64x64 tile re-reads each input mat 4x (1.1 GiB
//   at level 1) and the XCD-L2 working set (8 mats in flight x 512KB = 4MB)
//   exactly saturates the 4 MiB L2 -> partial reuse failure, HBM-bound tree.
//   128x128 halves the re-read factor (2+2) and needs only pairwise block
//   co-residency for L2 reuse.
//   - K staged in 4 steps: A[128x64] + B[64x128] bf16 = 32 KiB LDS.
//   - 4 waves, each owns a 64x64 quadrant: acc[4][4] f4, 128 MFMA/wave.
//   - epilogue devA/devB re-read from global (L2-hot), C stored directly
//     as u16 (32B segments/16 lanes) -- no C restage.
// Unchanged: fused tail, wide 8-launch tree, packed bf16 cvt, diag-hoist.
// ============================================================================

#define D 256
#define DD 65536

typedef __attribute__((ext_vector_type(8))) short short8;
typedef __attribute__((ext_vector_type(4))) float f4;

__device__ __forceinline__ float bf2f(unsigned short u) {
  return __uint_as_float(((unsigned)u) << 16);
}
__device__ __forceinline__ unsigned short f2bf(float f) {
  __hip_bfloat16 h = __float2bfloat16(f);
  unsigned short u;
  __builtin_memcpy(&u, &h, 2);
  return u;
}
__device__ __forceinline__ unsigned f2bf2(float lo, float hi) {
  __hip_bfloat162 h = __float22bfloat162_rn(make_float2(lo, hi));
  unsigned u;
  __builtin_memcpy(&u, &h, 4);
  return u;
}
// fragment-order slot lane index: frag reads lane-contiguous b128.
#define LSWZ(i15, lq) (((((i15) & 15)) + ((lq) << 4)) ^ (lq))
// slot for a 128(rows) x 64(k) bf16 LDS panel; element = slot*8 + (k&7)
#define PSLOT(r, k8) (((((r) >> 4) << 1) + ((k8) >> 5)) * 64 + LSWZ((r), ((k8) >> 3) & 3))

// out[mat] = devA + devB + devA@devB (bf16 dev out), MFMA 16x16x32 bf16.
// 128x128 tile/block (4 blocks/mat), 4 waves (2x2), K in 4 staged steps.
// Block swizzle: xcd = bx&7; all 4 tiles of a mat on the same XCD
// (requires gridDim/4 divisible by 8).
__global__ __launch_bounds__(256) void gemm_mfma(
    const float* __restrict__ aF, const unsigned short* __restrict__ aBf,
    long aMul, long aOff,
    const float* __restrict__ bF, const unsigned short* __restrict__ bBf,
    long bMul, long bOff,
    unsigned short* __restrict__ out)
{
  __shared__ __attribute__((aligned(16))) unsigned short As[8192]; // 16 KiB
  __shared__ __attribute__((aligned(16))) unsigned short Bs[8192]; // 16 KiB

  const int  bx  = blockIdx.x;
  const int  nmb = ((int)gridDim.x) >> 2;         // mats this dispatch (mult of 8)
  const int  xcd = bx & 7, q = bx >> 3;
  const long mat = (long)(xcd * (nmb >> 3)) + (q >> 2);
  const int  tile = q & 3;
  const int  m0 = (tile >> 1) << 7, n0 = (tile & 1) << 7;
  const long aBase = (mat * aMul + aOff) * (long)DD;
  const long bBase = (mat * bMul + bOff) * (long)DD;
  const int t = threadIdx.x;
  const int w = t >> 6, l = t & 63, lm = l & 15, lq4 = l >> 4;
  const int lswz = l ^ lq4;
  const int wr = w >> 1, wc = w & 1;              // wave quadrant (2x2)

  f4 acc[4][4];
#pragma unroll
  for (int i = 0; i < 4; ++i)
#pragma unroll
    for (int f = 0; f < 4; ++f)
      acc[i][f] = (f4){0.f, 0.f, 0.f, 0.f};

  for (int step = 0; step < 4; ++step) {
    const int kb = step << 6;
    // ---- stage A rows [m0,m0+128) x k[kb,kb+64): 4 cells/thread (8 k each)
    if (aF) {
#pragma unroll
      for (int p = 0; p < 4; ++p) {
        const int cell = t + (p << 8);
        const int row = cell >> 3, k8 = (cell & 7) << 3;
        const int rg = m0 + row, kg = kb + k8;
        const float* ap = aF + aBase + (long)rg * D + kg;
        float4 v0 = *(const float4*)ap;
        float4 v1 = *(const float4*)(ap + 4);
        const int dj = rg - kg;                   // diag in strip iff 0<=dj<8
        if (((unsigned)dj) < 8u) {
          if      (dj == 0) v0.x -= 1.f;
          else if (dj == 1) v0.y -= 1.f;
          else if (dj == 2) v0.z -= 1.f;
          else if (dj == 3) v0.w -= 1.f;
          else if (dj == 4) v1.x -= 1.f;
          else if (dj == 5) v1.y -= 1.f;
          else if (dj == 6) v1.z -= 1.f;
          else              v1.w -= 1.f;
        }
        union { short8 v8; unsigned u[4]; } ou;
        ou.u[0] = f2bf2(v0.x, v0.y); ou.u[1] = f2bf2(v0.z, v0.w);
        ou.u[2] = f2bf2(v1.x, v1.y); ou.u[3] = f2bf2(v1.z, v1.w);
        *(short8*)&As[PSLOT(row, k8) << 3] = ou.v8;
      }
    } else {
#pragma unroll
      for (int p = 0; p < 4; ++p) {
        const int cell = t + (p << 8);
        const int row = cell >> 3, k8 = (cell & 7) << 3;
        const short8 v = *(const short8*)(aBf + aBase + (long)(m0 + row) * D + kb + k8);
        *(short8*)&As[PSLOT(row, k8) << 3] = v;
      }
    }
    // ---- stage B cols [n0,n0+128) x k[kb,kb+64): 1 (4col x 8k) cell/thread
    {
      const int n4 = (t & 31) << 2;
      const int k8 = (t >> 5) << 3;
      const int gn = n0 + n4, kg = kb + k8;
      if (bF) {
        unsigned tmpu[4][4];
        const int rel = gn - kg;
#pragma unroll
        for (int h = 0; h < 2; ++h) {
          float4 va[2], vb[2];
#pragma unroll
          for (int p2 = 0; p2 < 2; ++p2) {
            va[p2] = *(const float4*)(bF + bBase + (long)(kg + 4 * h + 2 * p2) * D + gn);
            vb[p2] = *(const float4*)(bF + bBase + (long)(kg + 4 * h + 2 * p2 + 1) * D + gn);
          }
          if (rel == 4 * h) {                     // diag rows in this half
            va[0].x -= 1.f; vb[0].y -= 1.f; va[1].z -= 1.f; vb[1].w -= 1.f;
          }
          tmpu[0][2 * h + 0] = f2bf2(va[0].x, vb[0].x);
          tmpu[0][2 * h + 1] = f2bf2(va[1].x, vb[1].x);
          tmpu[1][2 * h + 0] = f2bf2(va[0].y, vb[0].y);
          tmpu[1][2 * h + 1] = f2bf2(va[1].y, vb[1].y);
          tmpu[2][2 * h + 0] = f2bf2(va[0].z, vb[0].z);
          tmpu[2][2 * h + 1] = f2bf2(va[1].z, vb[1].z);
          tmpu[3][2 * h + 0] = f2bf2(va[0].w, vb[0].w);
          tmpu[3][2 * h + 1] = f2bf2(va[1].w, vb[1].w);
        }
#pragma unroll
        for (int jj = 0; jj < 4; ++jj) {
          const int n = n4 + jj;
          uint4 st = { tmpu[jj][0], tmpu[jj][1], tmpu[jj][2], tmpu[jj][3] };
          *(uint4*)&Bs[PSLOT(n, k8) << 3] = st;
        }
      } else {
        __attribute__((aligned(16))) unsigned short tmp[4][8];
#pragma unroll
        for (int kk = 0; kk < 8; ++kk) {
          const ushort4 v = *(const ushort4*)(bBf + bBase + (long)(kg + kk) * D + gn);
          tmp[0][kk] = v.x; tmp[1][kk] = v.y; tmp[2][kk] = v.z; tmp[3][kk] = v.w;
        }
#pragma unroll
        for (int jj = 0; jj < 4; ++jj) {
          const int n = n4 + jj;
          *(uint4*)&Bs[PSLOT(n, k8) << 3] = *(const uint4*)&tmp[jj][0];
        }
      }
    }
    __syncthreads();
    // ---- MFMA: 2 kt x (4 a-frags, 4 b-frags, 16 MFMA)
#pragma unroll
    for (int kt = 0; kt < 2; ++kt) {
      short8 a_[4];
#pragma unroll
      for (int i = 0; i < 4; ++i)
        a_[i] = *(const short8*)&As[(((((wr << 2) + i) << 1) + kt) * 64 + lswz) << 3];
#pragma unroll
      for (int f = 0; f < 4; ++f) {
        const short8 b = *(const short8*)&Bs[(((((wc << 2) + f) << 1) + kt) * 64 + lswz) << 3];
#pragma unroll
        for (int i = 0; i < 4; ++i)
          acc[i][f] = __builtin_amdgcn_mfma_f32_16x16x32_bf16(a_[i], b, acc[i][f], 0, 0, 0);
      }
    }
    __syncthreads();
  }

  // ---- epilogue: s = acc + devA + devB (both global re-reads, L2-hot);
  //      direct bf16 u16 stores (16 lanes = 32B segments, L2-merged).
#pragma unroll
  for (int i = 0; i < 4; ++i) {
#pragma unroll
    for (int r = 0; r < 4; ++r) {
      const int rowg = m0 + (wr << 6) + (i << 4) + (lq4 << 2) + r;
      const long rA = aBase + (long)rowg * D;
      const long rB = bBase + (long)rowg * D;
      const long rO = mat * (long)DD + (long)rowg * D;
#pragma unroll
      for (int f = 0; f < 4; ++f) {
        const int colg = n0 + (wc << 6) + (f << 4) + lm;
        const float da = aF ? (aF[rA + colg] - ((rowg == colg) ? 1.f : 0.f))
                            : bf2f(aBf[rA + colg]);
        const float db = bF ? (bF[rB + colg] - ((rowg == colg) ? 1.f : 0.f))
                            : bf2f(bBf[rB + colg]);
        out[rO + colg] = f2bf(acc[i][f][r] + da + db);
      }
    }
  }
}

// v = v + v @ dev(M) over one bf16 span-product; barriers are WG-uniform.
__device__ __forceinline__ void apply_bf16(const unsigned short* __restrict__ Mb,
                                           float* v, float (*ps)[D],
                                           int t, int col, int kq) {
  const unsigned short* M = Mb + (long)(kq * 64) * D + col;
  float acc = 0.f;
#pragma unroll 8
  for (int i = 0; i < 64; ++i)
    acc += v[kq * 64 + i] * bf2f(M[(long)i * D]);
  ps[kq][col] = acc;
  __syncthreads();
  if (t < D) v[t] += ps[0][t] + ps[1][t] + ps[2][t] + ps[3][t];
  __syncthreads();
}

// ONE kernel for the whole tail. WG c targets prefix length L = 4c:
// greedy span descent (128*,64,32,16,8,4), then exact fp32 bottom mat-vecs
// over m emitting out rows L..L+3 (c=255 also emits row 1024).
__global__ __launch_bounds__(1024) void tail_fused(
    const float* __restrict__ x,
    const unsigned short* __restrict__ sp128, const unsigned short* __restrict__ sp64,
    const unsigned short* __restrict__ sp32,  const unsigned short* __restrict__ sp16,
    const unsigned short* __restrict__ sp8,   const unsigned short* __restrict__ sp4,
    const float* __restrict__ m, float* __restrict__ out)
{
  __shared__ float v[D];
  __shared__ float ps[4][D];
  const int c = blockIdx.x, t = threadIdx.x, col = t & 255, kq = t >> 8;
  if (t < D) v[t] = x[t];
  __syncthreads();
  const int L = c << 2;

  int pos = 0;
#pragma unroll 1
  while (pos + 128 <= L) { apply_bf16(sp128 + (long)(pos >> 7) * DD, v, ps, t, col, kq); pos += 128; }
  if (pos + 64 <= L) { apply_bf16(sp64 + (long)(pos >> 6) * DD, v, ps, t, col, kq); pos += 64; }
  if (pos + 32 <= L) { apply_bf16(sp32 + (long)(pos >> 5) * DD, v, ps, t, col, kq); pos += 32; }
  if (pos + 16 <= L) { apply_bf16(sp16 + (long)(pos >> 4) * DD, v, ps, t, col, kq); pos += 16; }
  if (pos + 8 <= L)  { apply_bf16(sp8  + (long)(pos >> 3) * DD, v, ps, t, col, kq); pos += 8; }
  if (pos + 4 <= L)  { apply_bf16(sp4  + (long)(pos >> 2) * DD, v, ps, t, col, kq); pos += 4; }

  // bottom: emit rows with exact fp32 mat-vecs over m
  if (t < D) out[(long)L * D + t] = v[t];
  const int steps = (c == 255) ? 4 : 3;
#pragma unroll 1
  for (int s = 0; s < steps; ++s) {
    const float* M = m + (long)(L + s) * DD + (long)(kq * 64) * D + col;
    float acc = 0.f;
#pragma unroll 8
    for (int i = 0; i < 64; ++i)
      acc += v[kq * 64 + i] * M[(long)i * D];
    ps[kq][col] = acc;
    __syncthreads();
    if (t < D) {
      const float s2 = ps[0][t] + ps[1][t] + ps[2][t] + ps[3][t];
      v[t] = s2;
      out[(long)(L + s + 1) * D + t] = s2;
    }
    __syncthreads();
  }
}

// correctness-only fallback if ws is too small: fully sequential chain
__global__ __launch_bounds__(256) void fallback_seq(
    const float* __restrict__ x, const float* __restrict__ m,
    float* __restrict__ out)
{
  __shared__ float v[D];
  const int t = threadIdx.x;
  v[t] = x[t];
  __syncthreads();
  for (int k = 0; k < 1024; ++k) {
    out[(long)k * D + t] = v[t];
    const float* M = m + (long)k * DD;
    float acc = 0.f;
    for (int i = 0; i < D; ++i) acc += v[i] * M[(long)i * D + t];
    __syncthreads();
    v[t] = acc;
    __syncthreads();
  }
  out[(long)1024 * D + t] = v[t];
}

extern "C" void kernel_launch(void* const* d_in, const int* in_sizes, int n_in,
                              void* d_out, int out_size, void* d_ws, size_t ws_size,
                              hipStream_t stream) {
  const float* x = (const float*)d_in[0];   // [1,256] fp32
  const float* m = (const float*)d_in[1];   // [1024,256,256] fp32
  float* out = (float*)d_out;               // [1025,256] fp32

  char* w8 = (char*)d_ws;
  const size_t MB = 1048576;
  const dim3 blk(256), vblk(1024);

  if (ws_size >= 127 * MB) {
    // ---- wide path: full-width tree, one launch per level (7 gemms + tail)
    unsigned short* T2   = (unsigned short*)(w8);             // 64 MiB span-2  (512)
    unsigned short* Qb   = (unsigned short*)(w8 + 64 * MB);   // 32 MiB span-4  (256)
    unsigned short* Q2   = (unsigned short*)(w8 + 96 * MB);   // 16 MiB span-8  (128)
    unsigned short* Q4   = (unsigned short*)(w8 + 112 * MB);  //  8 MiB span-16 (64)
    unsigned short* Rm   = (unsigned short*)(w8 + 120 * MB);  //  4 MiB span-32 (32)
    unsigned short* S64  = (unsigned short*)(w8 + 124 * MB);  //  2 MiB span-64 (16)
    unsigned short* S128 = (unsigned short*)(w8 + 126 * MB);  //  1 MiB span-128 (8)
    gemm_mfma<<<dim3(2048), blk, 0, stream>>>(m, nullptr, 2, 0, m, nullptr, 2, 1, T2);
    gemm_mfma<<<dim3(1024), blk, 0, stream>>>(nullptr, T2, 2, 0, nullptr, T2, 2, 1, Qb);
    gemm_mfma<<<dim3(512),  blk, 0, stream>>>(nullptr, Qb, 2, 0, nullptr, Qb, 2, 1, Q2);
    gemm_mfma<<<dim3(256),  blk, 0, stream>>>(nullptr, Q2, 2, 0, nullptr, Q2, 2, 1, Q4);
    gemm_mfma<<<dim3(128),  blk, 0, stream>>>(nullptr, Q4, 2, 0, nullptr, Q4, 2, 1, Rm);
    gemm_mfma<<<dim3(64),   blk, 0, stream>>>(nullptr, Rm, 2, 0, nullptr, Rm, 2, 1, S64);
    gemm_mfma<<<dim3(32),   blk, 0, stream>>>(nullptr, S64, 2, 0, nullptr, S64, 2, 1, S128);
    tail_fused<<<dim3(256), vblk, 0, stream>>>(x, S128, S64, Rm, Q4, Q2, Qb, m, out);
  } else if (ws_size >= 67108864) {
    // ---- narrow path (half-split tree), fused tail
    unsigned short* buf0 = (unsigned short*)(w8);
    unsigned short* Qb   = (unsigned short*)(w8 + 33554432);  // span-4, 256 mats
    unsigned short* Q2   = (unsigned short*)(w8);             // 16 MiB span-8
    unsigned short* Q4   = (unsigned short*)(w8 + 16777216);  //  8 MiB span-16
    unsigned short* Rm   = (unsigned short*)(w8 + 25165824);  //  4 MiB span-32
    unsigned short* S64  = (unsigned short*)(w8 + 29360128);  //  2 MiB span-64
    unsigned short* S128 = (unsigned short*)(w8 + 31457280);  //  1 MiB span-128
    gemm_mfma<<<dim3(1024), blk, 0, stream>>>(m, nullptr, 2, 0, m, nullptr, 2, 1, buf0);
    gemm_mfma<<<dim3(512),  blk, 0, stream>>>(nullptr, buf0, 2, 0, nullptr, buf0, 2, 1, Qb);
    gemm_mfma<<<dim3(1024), blk, 0, stream>>>(m + 512L * DD, nullptr, 2, 0,
                                              m + 512L * DD, nullptr, 2, 1, buf0);
    gemm_mfma<<<dim3(512),  blk, 0, stream>>>(nullptr, buf0, 2, 0, nullptr, buf0, 2, 1,
                                              Qb + 128L * DD);
    gemm_mfma<<<dim3(512),  blk, 0, stream>>>(nullptr, Qb, 2, 0, nullptr, Qb, 2, 1, Q2);
    gemm_mfma<<<dim3(256),  blk, 0, stream>>>(nullptr, Q2, 2, 0, nullptr, Q2, 2, 1, Q4);
    gemm_mfma<<<dim3(128),  blk, 0, stream>>>(nullptr, Q4, 2, 0, nullptr, Q4, 2, 1, Rm);
    gemm_mfma<<<dim3(64),   blk, 0, stream>>>(nullptr, Rm, 2, 0, nullptr, Rm, 2, 1, S64);
    gemm_mfma<<<dim3(32),   blk, 0, stream>>>(nullptr, S64, 2, 0, nullptr, S64, 2, 1, S128);
    tail_fused<<<dim3(256), vblk, 0, stream>>>(x, S128, S64, Rm, Q4, Q2, Qb, m, out);
  } else {
    fallback_seq<<<dim3(1), blk, 0, stream>>>(x, m, out);
  }
}